// Round 8
// baseline (77.573 us; speedup 1.0000x reference)
//
#include <hip/hip_runtime.h>
#include <hip/hip_bf16.h>
#include <cstdint>

// Problem constants (N read from in_sizes at launch; C, D fixed by reference).
#define DIM 64
#define NC  1024

#define AS1 __attribute__((address_space(1)))
#define AS3 __attribute__((address_space(3)))

typedef __attribute__((ext_vector_type(8))) __bf16 bf16x8;
typedef __attribute__((ext_vector_type(8))) short short8;
typedef __attribute__((ext_vector_type(4))) float f32x4;
typedef __attribute__((ext_vector_type(4))) unsigned int uint4v;

static __device__ __forceinline__ unsigned short f32_to_bf16_rne(float f) {
    unsigned int u = __builtin_bit_cast(unsigned int, f);
    unsigned int r = u + 0x7FFFu + ((u >> 16) & 1u);
    return (unsigned short)(r >> 16);
}
static __device__ __forceinline__ float bf16_bits_to_f32(unsigned short h) {
    return __builtin_bit_cast(float, (unsigned int)h << 16);
}
// Async 16B global->LDS (HW writes lds_base(uniform) + lane*16).
static __device__ __forceinline__ void gload_lds16(const void* g, void* l) {
    __builtin_amdgcn_global_load_lds((const AS1 unsigned int*)g,
                                     (AS3 unsigned int*)l, 16, 0, 0);
}

// ---------------------------------------------------------------------------
// Prep 1: normalized |coefs| weights -> wc2[c].x    (1 block, 1024 threads)
// ---------------------------------------------------------------------------
__global__ void coef_kernel(const float* __restrict__ coefs,
                            float2* __restrict__ wc2) {
    __shared__ float red[NC];
    const int c = threadIdx.x;
    const float a = fabsf(coefs[c]);
    red[c] = a;
    __syncthreads();
    for (int s = NC / 2; s > 0; s >>= 1) {
        if (c < s) red[c] += red[c + s];
        __syncthreads();
    }
    const float sum = red[0];
    const float w = (sum == 0.0f) ? a : a / sum;
    wc2[c].x = w;
}

// ---------------------------------------------------------------------------
// Prep 2: per-center c2 as a bf16 (hi, residual) pair packed in wc2[c].y;
// bf16(-2*centers) in MFMA B-fragment layout -> bfrag.
// Grid: NC/64 blocks x 64 threads, one center per thread.
//
// B-fragment layout for mfma_f32_16x16x32_bf16:
//   lane supplies B[k][col] with col = lane&15, k = (lane>>4)*8 + j.
//   Stored as bfrag[(tile*2 + kb)*64 + lane] : short8 (16B per lane).
// ---------------------------------------------------------------------------
__global__ void center_kernel(const float* __restrict__ centers,
                              float2* __restrict__ wc2,
                              short8* __restrict__ bfrag) {
    const int c = blockIdx.x * 64 + threadIdx.x;
    const float4* row = (const float4*)(centers + (size_t)c * DIM);

    float vals[DIM];
    float c2 = 0.0f;
#pragma unroll
    for (int q = 0; q < DIM / 4; ++q) {
        float4 v = row[q];
        vals[q * 4 + 0] = v.x; vals[q * 4 + 1] = v.y;
        vals[q * 4 + 2] = v.z; vals[q * 4 + 3] = v.w;
        c2 = fmaf(v.x, v.x, c2); c2 = fmaf(v.y, v.y, c2);
        c2 = fmaf(v.z, v.z, c2); c2 = fmaf(v.w, v.w, c2);
    }
    // hi + residual bf16 split: k=0 slot carries hi, k=1 slot carries lo.
    const unsigned short hi = f32_to_bf16_rne(c2);
    const unsigned short lo = f32_to_bf16_rne(c2 - bf16_bits_to_f32(hi));
    const unsigned int packed = (unsigned int)hi | ((unsigned int)lo << 16);
    wc2[c].y = __builtin_bit_cast(float, packed);

    const int tile = c >> 4;
    const int colL = c & 15;
#pragma unroll
    for (int kb = 0; kb < 2; ++kb) {
#pragma unroll
        for (int h = 0; h < 4; ++h) {
            short8 p;
#pragma unroll
            for (int j = 0; j < 8; ++j) {
                float v = -2.0f * vals[kb * 32 + h * 8 + j];
                p[j] = (short)f32_to_bf16_rne(v);
            }
            bfrag[(tile * 2 + kb) * 64 + (h * 16 + colL)] = p;
        }
    }
}

// ---------------------------------------------------------------------------
// Main: block = 256 threads = 4 waves (r4's proven row/center structure).
//   pairIdx = wave>>1 owns rows [blockBase + pairIdx*64, +64);
//   halfC   = wave&1 owns a 512-center half (32 tiles).
// B-path: 8 chunks of {4 tiles per half} = 16 KB staged per chunk into
// double-buffered LDS via async global_load_lds (16B) — zero register cost
// for in-flight data, B read from L2 ONCE per block (shared by waves).
// One __syncthreads per chunk (its implicit vmcnt drain publishes the
// staged buffer). Chunk loop pinned rolled (round-6 spill lesson).
// Per tile t (16 centers):
//   acc = mfma(ones[1,1,0..], bc2(t), C = x2)   // acc = x2 + c2 (matrix pipe)
//   acc = mfma(A0, B0(t), acc); acc = mfma(A1, B1(t), acc)  // acc = d^2
//   epilogue: d = sqrt(|acc|); sum = fma(w, d, sum)
// Final: shfl-reduce over 16 col-lanes, LDS-combine halves, write 128 rows.
// ---------------------------------------------------------------------------
__global__ __launch_bounds__(256, 4) void dist_kernel(
    const float* __restrict__ x,
    const float2* __restrict__ wc2,
    const char* __restrict__ bfragB,   // byte view of bfrag
    const float* __restrict__ madp,
    float* __restrict__ out)
{
    const int lane = threadIdx.x & 63;
    const int wave = threadIdx.x >> 6;
    const int lo = lane & 15;
    const int hi = lane >> 4;
    const int pairIdx = wave >> 1;     // row-group selector
    const int halfC  = wave & 1;       // center-half selector
    const int rowBase = blockIdx.x * 128 + pairIdx * 64;

    // LDS: double-buffered chunk [buf][half(8KB) | half(8KB)] + partials.
    __shared__ char lbuf[2][16384];
    __shared__ float part[4][64];

    bf16x8 afrag[4][2];
    f32x4 x2c[4];

    // ---- Kick off chunk-0 staging before the prologue (overlaps A loads).
    // Piece p = wave*4+q (0..15): pieces 0..7 = half0 tiles 0..3 (8KB span),
    // pieces 8..15 = half1 tiles 32..35. Contiguous 1KB per instruction.
    {
        const char* span0 = bfragB;                 // tiles 0..3
        const char* span1 = bfragB + 32 * 2048;     // tiles 32..35
#pragma unroll
        for (int q = 0; q < 4; ++q) {
            const int p = wave * 4 + q;
            const char* src = ((p < 8) ? span0 + p * 1024
                                       : span1 + (p - 8) * 1024) + lane * 16;
            gload_lds16(src, &lbuf[0][p * 1024]);
        }
    }

    // ---- Prologue: load A rows, bf16 fragments, x2 per row.
#pragma unroll
    for (int g = 0; g < 4; ++g) {
        const int row = rowBase + g * 16 + lo;
        const float* rp = x + (size_t)row * DIM + hi * 8;
        float s2 = 0.0f;
#pragma unroll
        for (int kb = 0; kb < 2; ++kb) {
            float4 v0 = *(const float4*)(rp + kb * 32);
            float4 v1 = *(const float4*)(rp + kb * 32 + 4);
            float vv[8] = {v0.x, v0.y, v0.z, v0.w, v1.x, v1.y, v1.z, v1.w};
            short8 p;
#pragma unroll
            for (int j = 0; j < 8; ++j) {
                s2 = fmaf(vv[j], vv[j], s2);
                p[j] = (short)f32_to_bf16_rne(vv[j]);
            }
            afrag[g][kb] = __builtin_bit_cast(bf16x8, p);
        }
        s2 += __shfl_xor(s2, 16, 64);
        s2 += __shfl_xor(s2, 32, 64);
#pragma unroll
        for (int b = 0; b < 4; ++b)
            x2c[g][b] = __shfl(s2, hi * 4 + b, 64);
    }

    // Constant A fragment [1,1,0,...,0] (k=0,1 live in the hi==0 lane group).
    const unsigned int ao = (hi == 0) ? 0x3F803F80u : 0u;
    const bf16x8 afones = __builtin_bit_cast(bf16x8, (uint4v){ao, 0u, 0u, 0u});

    float sum[4][4];
#pragma unroll
    for (int g = 0; g < 4; ++g)
#pragma unroll
        for (int b = 0; b < 4; ++b) sum[g][b] = 0.0f;

    // wc scalars for chunk 0 (tiles halfC*32 + 0..3).
    const float2* wp = wc2 + lo;
    float2 wcur[4], wnxt[4];
#pragma unroll
    for (int lt = 0; lt < 4; ++lt)
        wcur[lt] = wp[(halfC * 32 + lt) * 16];

    __syncthreads();   // drains vmcnt: chunk 0 staged, all waves ready

    const int myLds = halfC * 8192;    // this wave's half within a buffer

#pragma unroll 1   // MUST stay rolled (round 6: full unroll -> spill)
    for (int c = 0; c < 8; ++c) {
        const int cb = c & 1;

        // Stage chunk c+1 into the other buffer (flies under compute).
        if (c + 1 < 8) {
            const char* span0 = bfragB + (c + 1) * 8192;
            const char* span1 = bfragB + 32 * 2048 + (c + 1) * 8192;
#pragma unroll
            for (int q = 0; q < 4; ++q) {
                const int p = wave * 4 + q;
                const char* src = ((p < 8) ? span0 + p * 1024
                                           : span1 + (p - 8) * 1024) + lane * 16;
                gload_lds16(src, &lbuf[cb ^ 1][p * 1024]);
            }
#pragma unroll
            for (int lt = 0; lt < 4; ++lt)
                wnxt[lt] = wp[(halfC * 32 + (c + 1) * 4 + lt) * 16];
        }

        // Compute the 4 tiles of this chunk's half.
#pragma unroll
        for (int lt = 0; lt < 4; ++lt) {
            const float2 wc = wcur[lt];
            const float w = wc.x;
            const unsigned int packed = __builtin_bit_cast(unsigned int, wc.y);
            const bf16x8 bc2 = __builtin_bit_cast(bf16x8,
                (uint4v){(hi == 0) ? packed : 0u, 0u, 0u, 0u});
            const char* tp = &lbuf[cb][myLds + lt * 2048 + lane * 16];
            const bf16x8 b0 = *(const bf16x8*)tp;
            const bf16x8 b1 = *(const bf16x8*)(tp + 1024);

#pragma unroll
            for (int g = 0; g < 4; ++g) {
                f32x4 acc;
                acc = __builtin_amdgcn_mfma_f32_16x16x32_bf16(afones, bc2, x2c[g], 0, 0, 0);
                acc = __builtin_amdgcn_mfma_f32_16x16x32_bf16(afrag[g][0], b0, acc, 0, 0, 0);
                acc = __builtin_amdgcn_mfma_f32_16x16x32_bf16(afrag[g][1], b1, acc, 0, 0, 0);
#pragma unroll
                for (int b = 0; b < 4; ++b) {
                    float d = __builtin_amdgcn_sqrtf(fabsf(acc[b]));
                    sum[g][b] = fmaf(w, d, sum[g][b]);
                }
            }
        }

        __syncthreads();   // implicit vmcnt+lgkm drain: publishes chunk c+1
#pragma unroll
        for (int lt = 0; lt < 4; ++lt) wcur[lt] = wnxt[lt];
    }

    // Reduce over the 16 col-lanes of this wave's half, park in LDS.
#pragma unroll
    for (int g = 0; g < 4; ++g) {
#pragma unroll
        for (int b = 0; b < 4; ++b) {
            float v = sum[g][b];
            v += __shfl_xor(v, 1, 64);
            v += __shfl_xor(v, 2, 64);
            v += __shfl_xor(v, 4, 64);
            v += __shfl_xor(v, 8, 64);
            if (lo == 0) part[wave][g * 16 + hi * 4 + b] = v;
        }
    }
    __syncthreads();

    // Combine the two center-halves and write 128 rows.
    const int tid = threadIdx.x;
    if (tid < 128) {
        const int p = tid >> 6;
        const int r = tid & 63;
        const float s = part[2 * p][r] + part[2 * p + 1][r];
        out[blockIdx.x * 128 + p * 64 + r] = madp[0] - s;
    }
}

extern "C" void kernel_launch(void* const* d_in, const int* in_sizes, int n_in,
                              void* d_out, int out_size, void* d_ws, size_t ws_size,
                              hipStream_t stream) {
    const float* x       = (const float*)d_in[0];
    const float* centers = (const float*)d_in[1];
    const float* coefs   = (const float*)d_in[2];
    const float* mad     = (const float*)d_in[3];
    float* out = (float*)d_out;

    float2* wc2   = (float2*)d_ws;
    short8* bfrag = (short8*)((char*)d_ws + NC * sizeof(float2));

    const int N = in_sizes[0] / DIM;

    coef_kernel<<<1, NC, 0, stream>>>(coefs, wc2);
    center_kernel<<<NC / 64, 64, 0, stream>>>(centers, wc2, bfrag);
    dist_kernel<<<N / 128, 256, 0, stream>>>(x, wc2, (const char*)bfrag, mad, out);
}

// Round 9
// 46.102 us; speedup vs baseline: 1.6826x; 1.6826x over previous
//
#include <hip/hip_runtime.h>
#include <hip/hip_bf16.h>
#include <cstdint>

// Problem constants (N read from in_sizes at launch; C, D fixed by reference).
#define DIM 64
#define NC  1024
#define PF  2   // register-pipeline depth (tiles in flight)

typedef __attribute__((ext_vector_type(8))) __bf16 bf16x8;
typedef __attribute__((ext_vector_type(8))) short short8;
typedef __attribute__((ext_vector_type(4))) float f32x4;
typedef __attribute__((ext_vector_type(4))) unsigned int uint4v;

static __device__ __forceinline__ unsigned short f32_to_bf16_rne(float f) {
    unsigned int u = __builtin_bit_cast(unsigned int, f);
    unsigned int r = u + 0x7FFFu + ((u >> 16) & 1u);
    return (unsigned short)(r >> 16);
}
static __device__ __forceinline__ float bf16_bits_to_f32(unsigned short h) {
    return __builtin_bit_cast(float, (unsigned int)h << 16);
}

// ---------------------------------------------------------------------------
// Prep 1: normalized |coefs| weights -> wc2[c].x    (1 block, 1024 threads)
// ---------------------------------------------------------------------------
__global__ void coef_kernel(const float* __restrict__ coefs,
                            float2* __restrict__ wc2) {
    __shared__ float red[NC];
    const int c = threadIdx.x;
    const float a = fabsf(coefs[c]);
    red[c] = a;
    __syncthreads();
    for (int s = NC / 2; s > 0; s >>= 1) {
        if (c < s) red[c] += red[c + s];
        __syncthreads();
    }
    const float sum = red[0];
    const float w = (sum == 0.0f) ? a : a / sum;
    wc2[c].x = w;
}

// ---------------------------------------------------------------------------
// Prep 2: per-center c2 as a bf16 (hi, residual) pair packed in wc2[c].y;
// bf16(-2*centers) in MFMA B-fragment layout -> bfrag.
// Grid: NC/64 blocks x 64 threads, one center per thread.
//
// B-fragment layout for mfma_f32_16x16x32_bf16:
//   lane supplies B[k][col] with col = lane&15, k = (lane>>4)*8 + j.
//   Stored as bfrag[(tile*2 + kb)*64 + lane] : short8 (16B per lane).
// ---------------------------------------------------------------------------
__global__ void center_kernel(const float* __restrict__ centers,
                              float2* __restrict__ wc2,
                              short8* __restrict__ bfrag) {
    const int c = blockIdx.x * 64 + threadIdx.x;
    const float4* row = (const float4*)(centers + (size_t)c * DIM);

    float vals[DIM];
    float c2 = 0.0f;
#pragma unroll
    for (int q = 0; q < DIM / 4; ++q) {
        float4 v = row[q];
        vals[q * 4 + 0] = v.x; vals[q * 4 + 1] = v.y;
        vals[q * 4 + 2] = v.z; vals[q * 4 + 3] = v.w;
        c2 = fmaf(v.x, v.x, c2); c2 = fmaf(v.y, v.y, c2);
        c2 = fmaf(v.z, v.z, c2); c2 = fmaf(v.w, v.w, c2);
    }
    // hi + residual bf16 split: k=0 slot carries hi, k=1 slot carries lo.
    const unsigned short hi = f32_to_bf16_rne(c2);
    const unsigned short lo = f32_to_bf16_rne(c2 - bf16_bits_to_f32(hi));
    const unsigned int packed = (unsigned int)hi | ((unsigned int)lo << 16);
    wc2[c].y = __builtin_bit_cast(float, packed);

    const int tile = c >> 4;
    const int colL = c & 15;
#pragma unroll
    for (int kb = 0; kb < 2; ++kb) {
#pragma unroll
        for (int h = 0; h < 4; ++h) {
            short8 p;
#pragma unroll
            for (int j = 0; j < 8; ++j) {
                float v = -2.0f * vals[kb * 32 + h * 8 + j];
                p[j] = (short)f32_to_bf16_rne(v);
            }
            bfrag[(tile * 2 + kb) * 64 + (h * 16 + colL)] = p;
        }
    }
}

// ---------------------------------------------------------------------------
// Main: block = 256 threads = 4 waves, block owns 64 rows + full C.
//   wave w = rg*2 + halfC:  rg = w>>1 owns rows [R + rg*32, +32) (2 tile16s);
//                           halfC = w&1 owns a 512-center half (32 tiles).
// -> 32 rows/wave halves the register footprint vs r4 (breaks the ~128-reg
//    unified-file residency cap) and doubles waves to 8192 = 32/CU demand.
// Cooperative prologue: each of the 4 waves converts ONE 16-row tile of x
// into LDS (bf16 A-fragments + x2) — x read once, no duplicated conversion
// (r7's mistake); barrier; each wave reads back its 2 tiles' fragments.
// Main loop = r4's proven body: global B loads (L2-resident bfrag), PF=2
// register pipeline, outer loop pinned rolled (r6 spill lesson).
// Per tile t (16 centers):
//   acc = mfma(ones[1,1,0..], bc2(t), C = x2)   // acc = x2 + c2 (matrix pipe)
//   acc = mfma(A0, B0(t), acc); acc = mfma(A1, B1(t), acc)  // acc = d^2
//   epilogue: d = sqrt(|acc|); sum = fma(w, d, sum)
// Final: shfl-reduce over 16 col-lanes, LDS-combine the two halves per
// row-group, write 64 rows.
// ---------------------------------------------------------------------------
__global__ __launch_bounds__(256, 4) void dist_kernel(
    const float* __restrict__ x,
    const float2* __restrict__ wc2,
    const bf16x8* __restrict__ bfrag,
    const float* __restrict__ madp,
    float* __restrict__ out)
{
    const int lane = threadIdx.x & 63;
    const int wave = threadIdx.x >> 6;
    const int lo = lane & 15;
    const int hi = lane >> 4;
    const int rg    = wave >> 1;       // row-group (32 rows) selector
    const int halfC = wave & 1;        // center-half selector
    const int R = blockIdx.x * 64;

    __shared__ short8 alds[8][64];            // [tile16*2+kb][lane] A-frags
    __shared__ __align__(16) float x2lds[64]; // x2 per row (block's 64 rows)
    __shared__ float part[4][32];

    // ---- Cooperative prologue: wave w converts tile16 #w (rows R+16w..+15).
    {
        const int row = R + wave * 16 + lo;
        const float* rp = x + (size_t)row * DIM + hi * 8;
        float s2 = 0.0f;
#pragma unroll
        for (int kb = 0; kb < 2; ++kb) {
            float4 v0 = *(const float4*)(rp + kb * 32);
            float4 v1 = *(const float4*)(rp + kb * 32 + 4);
            float vv[8] = {v0.x, v0.y, v0.z, v0.w, v1.x, v1.y, v1.z, v1.w};
            short8 p;
#pragma unroll
            for (int j = 0; j < 8; ++j) {
                s2 = fmaf(vv[j], vv[j], s2);
                p[j] = (short)f32_to_bf16_rne(vv[j]);
            }
            alds[wave * 2 + kb][lane] = p;
        }
        // lane holds 16 of row lo's 64 values; combine the 4 hi-groups.
        s2 += __shfl_xor(s2, 16, 64);
        s2 += __shfl_xor(s2, 32, 64);
        if (hi == 0) x2lds[wave * 16 + lo] = s2;
    }
    __syncthreads();

    // ---- Read back this wave's 2 tiles (rows rg*32 .. +31).
    bf16x8 afrag[2][2];
    f32x4 x2c[2];
#pragma unroll
    for (int g = 0; g < 2; ++g) {
        const int t16 = rg * 2 + g;
#pragma unroll
        for (int kb = 0; kb < 2; ++kb)
            afrag[g][kb] = __builtin_bit_cast(bf16x8, alds[t16 * 2 + kb][lane]);
        x2c[g] = *(const f32x4*)&x2lds[t16 * 16 + hi * 4];
    }

    // Constant A fragment [1,1,0,...,0] (k=0,1 live in the hi==0 lane group).
    const unsigned int ao = (hi == 0) ? 0x3F803F80u : 0u;
    const bf16x8 afones = __builtin_bit_cast(bf16x8, (uint4v){ao, 0u, 0u, 0u});

    float sum[2][4];
#pragma unroll
    for (int g = 0; g < 2; ++g)
#pragma unroll
        for (int b = 0; b < 4; ++b) sum[g][b] = 0.0f;

    const int tbase = halfC * 32;        // 32 tiles = 512 centers per wave
    const bf16x8* bp = bfrag + lane;     // lane-fixed base
    const float2* wp = wc2 + lo;

    // Fill the register pipeline: slots j = tiles tbase+j.
    bf16x8 pb0[PF], pb1[PF];
    float2 pwc[PF];
#pragma unroll
    for (int j = 0; j < PF; ++j) {
        const int t = tbase + j;
        pb0[j] = bp[t * 128];
        pb1[j] = bp[t * 128 + 64];
        pwc[j] = wp[t * 16];
    }

#pragma unroll 1   // MUST stay rolled (round 6: full unroll -> spill)
    for (int i = 0; i < 32; i += PF) {
#pragma unroll
        for (int j = 0; j < PF; ++j) {
            const float2 wc = pwc[j];
            const float w = wc.x;
            const unsigned int packed = __builtin_bit_cast(unsigned int, wc.y);
            const bf16x8 bc2 = __builtin_bit_cast(bf16x8,
                (uint4v){(hi == 0) ? packed : 0u, 0u, 0u, 0u});
            const bf16x8 b0 = pb0[j];
            const bf16x8 b1 = pb1[j];

            // Prefetch tile i+j+PF into slot j (wrap at tail; harmless).
            {
                const int nxt = i + j + PF;
                const int tn = tbase + ((nxt < 32) ? nxt : 0);
                pb0[j] = bp[tn * 128];
                pb1[j] = bp[tn * 128 + 64];
                pwc[j] = wp[tn * 16];
            }

#pragma unroll
            for (int g = 0; g < 2; ++g) {
                f32x4 acc;
                acc = __builtin_amdgcn_mfma_f32_16x16x32_bf16(afones, bc2, x2c[g], 0, 0, 0);
                acc = __builtin_amdgcn_mfma_f32_16x16x32_bf16(afrag[g][0], b0, acc, 0, 0, 0);
                acc = __builtin_amdgcn_mfma_f32_16x16x32_bf16(afrag[g][1], b1, acc, 0, 0, 0);
#pragma unroll
                for (int b = 0; b < 4; ++b) {
                    float d = __builtin_amdgcn_sqrtf(fabsf(acc[b]));
                    sum[g][b] = fmaf(w, d, sum[g][b]);
                }
            }
        }
    }

    // Reduce over the 16 col-lanes of this wave's half, park in LDS.
#pragma unroll
    for (int g = 0; g < 2; ++g) {
#pragma unroll
        for (int b = 0; b < 4; ++b) {
            float v = sum[g][b];
            v += __shfl_xor(v, 1, 64);
            v += __shfl_xor(v, 2, 64);
            v += __shfl_xor(v, 4, 64);
            v += __shfl_xor(v, 8, 64);
            if (lo == 0) part[wave][g * 16 + hi * 4 + b] = v;
        }
    }
    __syncthreads();

    // Combine the two center-halves per row-group and write 64 rows.
    const int tid = threadIdx.x;
    if (tid < 64) {
        const int r2 = tid >> 5;       // row-group
        const int r  = tid & 31;       // row within group
        const float s = part[r2 * 2][r] + part[r2 * 2 + 1][r];
        out[R + r2 * 32 + r] = madp[0] - s;
    }
}

extern "C" void kernel_launch(void* const* d_in, const int* in_sizes, int n_in,
                              void* d_out, int out_size, void* d_ws, size_t ws_size,
                              hipStream_t stream) {
    const float* x       = (const float*)d_in[0];
    const float* centers = (const float*)d_in[1];
    const float* coefs   = (const float*)d_in[2];
    const float* mad     = (const float*)d_in[3];
    float* out = (float*)d_out;

    float2* wc2   = (float2*)d_ws;
    short8* bfrag = (short8*)((char*)d_ws + NC * sizeof(float2));

    const int N = in_sizes[0] / DIM;

    coef_kernel<<<1, NC, 0, stream>>>(coefs, wc2);
    center_kernel<<<NC / 64, 64, 0, stream>>>(centers, wc2, bfrag);
    dist_kernel<<<N / 64, 256, 0, stream>>>(x, wc2, (const bf16x8*)bfrag, mad, out);
}